// Round 9
// baseline (48339.236 us; speedup 1.0000x reference)
//
#include <hip/hip_runtime.h>
#include <hip/hip_bf16.h>

// 2-layer GRU (torch gate order r,z,n) + residual, B=16 T=4096 IN=H=512.
//
// Round-9 = round-8 + XCD co-location of the h-exchange.
//  - 32 WGs, role by bx: xcd=bx&7, idx=bx>>3.
//      xcd 0: rec L1 (4 WGs, same XCD if dispatch round-robins bx%8)
//      xcd 1: rec L2 (4 WGs)         xcd 2/3: helpers L1 (8)
//      xcd 4/5: helpers L2 (8)       xcd 6/7: exit
//  - h poll: FIRST attempt with sc0-only loads (own-XCD L2, fast if the
//    producers' sc0sc1 stores populated it); retries use sc0sc1 (L3
//    authoritative) -> correct regardless of actual placement.
//  - helper L1 prefetches x(t+1) into registers across the step (tracked
//    loads; compiler-managed waits).
//  - hot h-retry loop: no s_sleep.
// Everything else identical to round 8 (tag-in-data rings, 4 rec WGs/layer
// holding W_hh quarters in 384 VGPR/lane, 8 helpers/layer streaming fp32 xg
// into 32-deep rings, prefetched xg/y, rare back-pressure polls).

namespace {

constexpr int SEQ   = 4096;
constexpr int HD    = 512;
constexpr int NSLOT = 32;          // ring depth (steps)
constexpr int XROW  = 3 * HD;      // 1536 gate rows
constexpr int ROWS  = 528;         // LDS row pitch (u16)
constexpr int SLOTU = 16 * HD;     // u32 per h slot

typedef short    bf16x8 __attribute__((ext_vector_type(8)));
typedef float    f32x4  __attribute__((ext_vector_type(4)));
typedef unsigned u32x4  __attribute__((ext_vector_type(4)));

__device__ __forceinline__ unsigned short f2bf(float f) {
  unsigned u = __float_as_uint(f);
  return (unsigned short)((u + 0x7fffu + ((u >> 16) & 1u)) >> 16);  // RNE
}
__device__ __forceinline__ float bf2f(unsigned short s) {
  return __uint_as_float(((unsigned)s) << 16);
}
__device__ __forceinline__ unsigned pack2(float lo, float hi) {
  return (unsigned)f2bf(lo) | ((unsigned)f2bf(hi) << 16);
}
__device__ __forceinline__ float sigm(float v) { return 1.f / (1.f + __expf(-v)); }
__device__ __forceinline__ float tanh_(float v) { return 1.f - 2.f / (1.f + __expf(2.f * v)); }

__device__ __forceinline__ void ld_u32x4_nw(u32x4* d, const unsigned* p) {
  asm volatile("global_load_dwordx4 %0, %1, off sc0 sc1" : "=v"(*d) : "v"(p) : "memory");
}
// sc0-only: L1-bypass, served by own-XCD L2 (fast path; NOT authoritative
// cross-XCD -- callers must fall back to sc0sc1 on tag mismatch)
__device__ __forceinline__ void ld_u32x4_l2(u32x4* d, const unsigned* p) {
  asm volatile("global_load_dwordx4 %0, %1, off sc0" : "=v"(*d) : "v"(p) : "memory");
}
__device__ __forceinline__ void ld_f32x4_sc(f32x4* d, const float* p) {
  asm volatile("global_load_dwordx4 %0, %1, off sc0 sc1" : "=v"(*d) : "v"(p) : "memory");
}
__device__ __forceinline__ void st_u32_sc(unsigned* p, unsigned v) {
  asm volatile("global_store_dword %0, %1, off sc0 sc1" :: "v"(p), "v"(v) : "memory");
}
__device__ __forceinline__ void st_f32_sc(float* p, float v) {
  asm volatile("global_store_dword %0, %1, off sc0 sc1" :: "v"(p), "v"(v) : "memory");
}
__device__ __forceinline__ void st_u32x4_sc(unsigned* p, u32x4 v) {
  asm volatile("global_store_dwordx4 %0, %1, off sc0 sc1" :: "v"(p), "v"(v) : "memory");
}
__device__ __forceinline__ void vmwait0() {
  asm volatile("s_waitcnt vmcnt(0)" ::: "memory");
  __builtin_amdgcn_sched_barrier(0);   // rule #18
}

#define MFMA16(a, b, c) __builtin_amdgcn_mfma_f32_16x16x32_bf16((a), (b), (c), 0, 0, 0)

// hi16 extraction of 8 tagged granules -> 4x b128 LDS writes (padded rows)
__device__ __forceinline__ void stage_lds(const u32x4 (&v)[8], short* base, int b, int kc) {
  char* rowp = (char*)(base + b * ROWS + kc * 32);
  #pragma unroll
  for (int blk = 0; blk < 4; ++blk) {
    const int bb = blk ^ (kc & 3);
    const u32x4 a = v[bb * 2], d = v[bb * 2 + 1];
    u32x4 p;
    p[0] = (a[0] >> 16) | (a[1] & 0xffff0000u);
    p[1] = (a[2] >> 16) | (a[3] & 0xffff0000u);
    p[2] = (d[0] >> 16) | (d[1] & 0xffff0000u);
    p[3] = (d[2] >> 16) | (d[3] & 0xffff0000u);
    *(u32x4*)(rowp + bb * 16) = p;
  }
}

__device__ __forceinline__ void stage_x(const f32x4 (&xl)[8], short* base, int b, int kc) {
  char* rowp = (char*)(base + b * ROWS + kc * 32);
  #pragma unroll
  for (int blk = 0; blk < 4; ++blk) {
    const int bb = blk ^ (kc & 3);
    const f32x4 a = xl[bb * 2], d = xl[bb * 2 + 1];
    u32x4 p;
    p[0] = pack2(a[0], a[1]);
    p[1] = pack2(a[2], a[3]);
    p[2] = pack2(d[0], d[1]);
    p[3] = pack2(d[2], d[3]);
    *(u32x4*)(rowp + bb * 16) = p;
  }
}

// ---------------- recurrence WG: 256 thr, owns 128 units ----------------
template <int LAYER>
__device__ void rec_fn(const float* __restrict__ Whh, const float* __restrict__ bhh,
                       unsigned* ctl, unsigned* hr1, unsigned* hr2,
                       float* xgr, float* __restrict__ out, int s, char* smem) {
  short*    hstage = (short*)smem;                         // [2][16][528]  33792B
  float*    stash  = (float*)(smem + 33792);               // [2][256][24]  49152B
  unsigned* ylds   = (unsigned*)(smem + 33792 + 49152);    // [2][256][8]   16384B
  float*    gb     = (float*)(smem + 99328);               // [16][400]     25600B
  float*    bhl    = (float*)(smem + 124928);              // [384]          1536B

  const int tid = threadIdx.x;
  const int w = tid >> 6, lane = tid & 63, c = lane & 15, q = lane >> 4;
  const int b = tid >> 4, kc = tid & 15;      // staging + epilogue batch
  const int u0 = kc * 8;                      // epilogue unit base (local)

  unsigned* ownring = LAYER ? hr2 : hr1;
  unsigned* recprog = ctl + LAYER * 4;
  unsigned* xgtag   = ctl + 64 + LAYER * (NSLOT * 8);
  unsigned* recprog2 = ctl + 4;
  unsigned* xgtag2   = ctl + 64 + (NSLOT * 8);

  for (int i = tid; i < 384; i += 256) {
    const int g = i >> 7, u = i & 127;
    bhl[i] = bhh[g * HD + s * 128 + u];
  }
  // stationary W_hh: wave w -> local rows [w*96, w*96+96) (6 N-tiles)
  bf16x8 wf[6][16];
  #pragma unroll
  for (int nt = 0; nt < 6; ++nt) {
    const int lr = w * 96 + nt * 16 + c;
    const int g = lr >> 7, u = lr & 127;
    const float* pw = Whh + ((size_t)(g * HD + s * 128 + u)) * HD + q * 8;
    #pragma unroll
    for (int kk = 0; kk < 16; ++kk) {
      bf16x8 f;
      #pragma unroll
      for (int i = 0; i < 8; ++i) f[i] = (short)f2bf(pw[kk * 32 + i]);
      wf[nt][kk] = f;
    }
  }
  __syncthreads();

  f32x4 h0 = {0.f,0.f,0.f,0.f}, h1 = {0.f,0.f,0.f,0.f};  // own h fp32 (b,u0..u0+7)
  int haveXG = 0, haveY = 0;

  for (int t = 0; t < SEQ; ++t) {
    const int buf = t & 1, slot = t & (NSLOT - 1);
    // ------------- phase A -------------
    {
      if (LAYER == 0 && tid == 0 && t >= 32 && (t & 7) == 0) {
        // y-ring reuse: need L2 helpers + L2 rec past step t-24
        const unsigned need = (unsigned)(t - 23);
        const int ck = (t - 24) & (NSLOT - 1);
        for (;;) {
          u32x4 ta, tb, pr;
          ld_u32x4_nw(&ta, xgtag2 + ck * 8);
          ld_u32x4_nw(&tb, xgtag2 + ck * 8 + 4);
          ld_u32x4_nw(&pr, recprog2);
          vmwait0();
          bool ok = true;
          #pragma unroll
          for (int e = 0; e < 4; ++e)
            ok = ok && ta[e] >= need && tb[e] >= need && pr[e] >= need;
          if (ok) break;
          __builtin_amdgcn_s_sleep(32);
        }
      }
      // issue h loads (sc0 fast path) + xgtag(t+1) + y(t+1) together
      u32x4 hv[8];
      const unsigned htag = (unsigned)t;
      const unsigned* hp = ownring + (size_t)((t - 1) & (NSLOT - 1)) * SLOTU + b * HD + kc * 32;
      if (t > 0) {
        #pragma unroll
        for (int g2 = 0; g2 < 8; ++g2) ld_u32x4_l2(&hv[g2], hp + g2 * 4);
      }
      u32x4 tga = {0,0,0,0}, tgb = {0,0,0,0}, yv0 = {0,0,0,0}, yv1 = {0,0,0,0};
      const int nslot = (t + 1) & (NSLOT - 1);
      if (t + 1 < SEQ) {
        ld_u32x4_nw(&tga, xgtag + nslot * 8);
        ld_u32x4_nw(&tgb, xgtag + nslot * 8 + 4);
        if (LAYER == 1) {
          const unsigned* yp = hr1 + (size_t)nslot * SLOTU + b * HD + s * 128 + u0;
          ld_u32x4_nw(&yv0, yp);
          ld_u32x4_nw(&yv1, yp + 4);
        }
      }
      vmwait0();
      // h verify: sc0 result first; retries authoritative (sc0sc1), no sleep
      if (t > 0) {
        for (;;) {
          unsigned bad = 0;
          #pragma unroll
          for (int g2 = 0; g2 < 8; ++g2)
            #pragma unroll
            for (int e = 0; e < 4; ++e) bad |= hv[g2][e] ^ htag;
          if (!(bad & 0xffffu)) break;
          #pragma unroll
          for (int g2 = 0; g2 < 8; ++g2) ld_u32x4_nw(&hv[g2], hp + g2 * 4);
          vmwait0();
        }
        stage_lds(hv, hstage + buf * (16 * ROWS), b, kc);
      }
      // xg(t) fallback if not prefetched
      if (!haveXG) {
        const unsigned need = (unsigned)(t + 1);
        for (;;) {
          u32x4 ta, tb;
          ld_u32x4_nw(&ta, xgtag + slot * 8);
          ld_u32x4_nw(&tb, xgtag + slot * 8 + 4);
          vmwait0();
          bool ok = true;
          #pragma unroll
          for (int e = 0; e < 4; ++e) ok = ok && ta[e] == need && tb[e] == need;
          if (ok) break;
          __builtin_amdgcn_s_sleep(4);
        }
        f32x4 xv[6];
        const float* xp = xgr + ((size_t)slot * 16 + b) * XROW + s * 128 + u0;
        #pragma unroll
        for (int g2 = 0; g2 < 3; ++g2) {
          ld_f32x4_sc(&xv[g2 * 2],     xp + g2 * HD);
          ld_f32x4_sc(&xv[g2 * 2 + 1], xp + g2 * HD + 4);
        }
        vmwait0();
        float* st = stash + (buf * 256 + tid) * 24;
        #pragma unroll
        for (int g2 = 0; g2 < 6; ++g2) *(f32x4*)(st + g2 * 4) = xv[g2];
      }
      // y(t) fallback (L2 layer)
      if (LAYER == 1 && !haveY) {
        const unsigned need = (unsigned)(t + 1);
        const unsigned* yp = hr1 + (size_t)slot * SLOTU + b * HD + s * 128 + u0;
        u32x4 a0, a1;
        for (;;) {
          ld_u32x4_nw(&a0, yp);
          ld_u32x4_nw(&a1, yp + 4);
          vmwait0();
          unsigned bad = 0;
          #pragma unroll
          for (int e = 0; e < 4; ++e) bad |= (a0[e] ^ need) | (a1[e] ^ need);
          if (!(bad & 0xffffu)) break;
          __builtin_amdgcn_s_sleep(2);
        }
        unsigned* yd = ylds + (buf * 256 + tid) * 8;
        *(u32x4*)yd = a0;
        *(u32x4*)(yd + 4) = a1;
      }
      // prefetch xg(t+1) / y(t+1) if tags fresh
      haveXG = 0; haveY = 0;
      if (t + 1 < SEQ) {
        const unsigned need = (unsigned)(t + 2);
        bool okx = true;
        #pragma unroll
        for (int e = 0; e < 4; ++e) okx = okx && tga[e] == need && tgb[e] == need;
        if (okx) {
          f32x4 xv[6];
          const float* xp = xgr + ((size_t)nslot * 16 + b) * XROW + s * 128 + u0;
          #pragma unroll
          for (int g2 = 0; g2 < 3; ++g2) {
            ld_f32x4_sc(&xv[g2 * 2],     xp + g2 * HD);
            ld_f32x4_sc(&xv[g2 * 2 + 1], xp + g2 * HD + 4);
          }
          vmwait0();
          float* st = stash + ((buf ^ 1) * 256 + tid) * 24;
          #pragma unroll
          for (int g2 = 0; g2 < 6; ++g2) *(f32x4*)(st + g2 * 4) = xv[g2];
          haveXG = 1;
        }
        if (LAYER == 1) {
          unsigned bad = 0;
          #pragma unroll
          for (int e = 0; e < 4; ++e) bad |= (yv0[e] ^ need) | (yv1[e] ^ need);
          if (!(bad & 0xffffu)) {
            unsigned* yd = ylds + ((buf ^ 1) * 256 + tid) * 8;
            *(u32x4*)yd = yv0;
            *(u32x4*)(yd + 4) = yv1;
            haveY = 1;
          }
        }
      }
    }
    __syncthreads();  // B1
    if (tid == 255) st_u32_sc(&recprog[s], (unsigned)(t + 1));

    // ------------- matvec: 96 MFMA/wave -------------
    {
      f32x4 acc[6] = {{0.f,0.f,0.f,0.f},{0.f,0.f,0.f,0.f},{0.f,0.f,0.f,0.f},
                      {0.f,0.f,0.f,0.f},{0.f,0.f,0.f,0.f},{0.f,0.f,0.f,0.f}};
      if (t > 0) {
        const short* ap = hstage + buf * (16 * ROWS) + c * ROWS + q * 8;
        #pragma unroll
        for (int kk = 0; kk < 16; ++kk) {
          bf16x8 a = *(const bf16x8*)(ap + kk * 32);
          #pragma unroll
          for (int nt = 0; nt < 6; ++nt) acc[nt] = MFMA16(a, wf[nt][kk], acc[nt]);
        }
      }
      #pragma unroll
      for (int nt = 0; nt < 6; ++nt) {
        const int lr = w * 96 + nt * 16 + c;
        #pragma unroll
        for (int j = 0; j < 4; ++j) gb[(q * 4 + j) * 400 + lr] = acc[nt][j];
      }
    }
    __syncthreads();  // B2

    // ------------- epilogue -------------
    {
      const float* st = stash + (buf * 256 + tid) * 24;
      u32x4 pk0, pk1;
      float hv8[8];
      #pragma unroll
      for (int i = 0; i < 8; ++i) {
        const int u = u0 + i;
        const float xr_ = st[i], xz_ = st[8 + i], xn_ = st[16 + i];
        const float hr_ = gb[b * 400 + u] + bhl[u];
        const float hz_ = gb[b * 400 + 128 + u] + bhl[128 + u];
        const float hn_ = gb[b * 400 + 256 + u] + bhl[256 + u];
        const float r = sigm(xr_ + hr_);
        const float z = sigm(xz_ + hz_);
        const float nn = tanh_(xn_ + r * hn_);
        const float hp = (i < 4) ? h0[i & 3] : h1[i & 3];
        const float hv = (1.f - z) * nn + z * hp;
        if (i < 4) h0[i & 3] = hv; else h1[i & 3] = hv;
        hv8[i] = hv;
        const unsigned pw = ((unsigned)f2bf(hv) << 16) | (unsigned)(t + 1);
        if (i < 4) pk0[i & 3] = pw; else pk1[i & 3] = pw;
      }
      unsigned* op = ownring + (size_t)slot * SLOTU + b * HD + s * 128 + u0;
      st_u32x4_sc(op, pk0);
      st_u32x4_sc(op + 4, pk1);
      if (LAYER == 1) {
        const unsigned* yd = ylds + (buf * 256 + tid) * 8;
        f32x4 o0, o1;
        #pragma unroll
        for (int i = 0; i < 4; ++i) {
          o0[i] = hv8[i] + bf2f((unsigned short)(yd[i] >> 16));
          o1[i] = hv8[4 + i] + bf2f((unsigned short)(yd[4 + i] >> 16));
        }
        float* po = out + ((size_t)b * SEQ + t) * HD + s * 128 + u0;
        *(f32x4*)po = o0;
        *(f32x4*)(po + 4) = o1;
      }
    }
  }
}

// ---------------- helper WG: xg producer, 192 rows ----------------
template <int LAYER>
__device__ void helper_fn(const float* __restrict__ x,
                          const float* __restrict__ Wih, const float* __restrict__ bih,
                          unsigned* ctl, unsigned* hr1, float* xgr, int h, char* smem) {
  short* astage = (short*)smem;   // [16][528]
  const int tid = threadIdx.x;
  const int w = tid >> 6, lane = tid & 63, c = lane & 15, q = lane >> 4;
  const int b = tid >> 4, kc = tid & 15;
  unsigned* recprog = ctl + LAYER * 4;
  unsigned* xgtag   = ctl + 64 + LAYER * (NSLOT * 8);

  bf16x8 wfh[3][16];
  float bias[3];
  #pragma unroll
  for (int ti = 0; ti < 3; ++ti) {
    const int grow = h * 192 + w * 48 + ti * 16 + c;
    bias[ti] = bih[grow];
    const float* pw = Wih + (size_t)grow * HD + q * 8;
    #pragma unroll
    for (int kk = 0; kk < 16; ++kk) {
      bf16x8 f;
      #pragma unroll
      for (int i = 0; i < 8; ++i) f[i] = (short)f2bf(pw[kk * 32 + i]);
      wfh[ti][kk] = f;
    }
  }

  // L1 helper: x(t) prefetched into registers one step ahead (tracked loads)
  f32x4 xl[8];
  if (LAYER == 0) {
    const float* px = x + (size_t)b * SEQ * HD + kc * 32;
    #pragma unroll
    for (int g2 = 0; g2 < 8; ++g2) xl[g2] = *(const f32x4*)(px + g2 * 4);
  }

  for (int t = 0; t < SEQ; ++t) {
    const int slot = t & (NSLOT - 1);
    if (tid == 0 && t >= NSLOT && (t & 7) == 0) {
      const unsigned need = (unsigned)(t - 16);
      for (;;) {
        u32x4 pr;
        ld_u32x4_nw(&pr, recprog);
        vmwait0();
        if (pr[0] >= need && pr[1] >= need && pr[2] >= need && pr[3] >= need) break;
        __builtin_amdgcn_s_sleep(32);
      }
    }
    if (LAYER == 0) {
      stage_x(xl, astage, b, kc);
      if (t + 1 < SEQ) {
        const float* px = x + ((size_t)b * SEQ + (t + 1)) * HD + kc * 32;
        #pragma unroll
        for (int g2 = 0; g2 < 8; ++g2) xl[g2] = *(const f32x4*)(px + g2 * 4);
      }
    } else {
      // poll y_t chunk (tag-in-data)
      u32x4 v0[8];
      const unsigned* yp = hr1 + (size_t)slot * SLOTU + b * HD + kc * 32;
      const unsigned need = (unsigned)(t + 1);
      #pragma unroll
      for (int g2 = 0; g2 < 8; ++g2) ld_u32x4_nw(&v0[g2], yp + g2 * 4);
      vmwait0();
      for (;;) {
        unsigned bad = 0;
        #pragma unroll
        for (int g2 = 0; g2 < 8; ++g2)
          #pragma unroll
          for (int e = 0; e < 4; ++e) bad |= v0[g2][e] ^ need;
        if (!(bad & 0xffffu)) break;
        __builtin_amdgcn_s_sleep(1);
        #pragma unroll
        for (int g2 = 0; g2 < 8; ++g2) ld_u32x4_nw(&v0[g2], yp + g2 * 4);
        vmwait0();
      }
      stage_lds(v0, astage, b, kc);
    }
    __syncthreads();  // stage ready

    f32x4 acc[3] = {{0.f,0.f,0.f,0.f},{0.f,0.f,0.f,0.f},{0.f,0.f,0.f,0.f}};
    const short* ap = astage + c * ROWS + q * 8;
    #pragma unroll
    for (int kk = 0; kk < 16; ++kk) {
      bf16x8 a = *(const bf16x8*)(ap + kk * 32);
      #pragma unroll
      for (int ti = 0; ti < 3; ++ti) acc[ti] = MFMA16(a, wfh[ti][kk], acc[ti]);
    }
    #pragma unroll
    for (int ti = 0; ti < 3; ++ti) {
      const int grow = h * 192 + w * 48 + ti * 16 + c;
      #pragma unroll
      for (int j = 0; j < 4; ++j)
        st_f32_sc(xgr + ((size_t)slot * 16 + (q * 4 + j)) * XROW + grow,
                  acc[ti][j] + bias[ti]);
    }
    vmwait0();
    __syncthreads();  // all stores acked
    if (tid == 0) st_u32_sc(&xgtag[slot * 8 + h], (unsigned)(t + 1));
  }
}

__global__ __launch_bounds__(256, 1) void gru2_k(
    const float* __restrict__ x,
    const float* __restrict__ Wih1, const float* __restrict__ Whh1,
    const float* __restrict__ bih1, const float* __restrict__ bhh1,
    const float* __restrict__ Wih2, const float* __restrict__ Whh2,
    const float* __restrict__ bih2, const float* __restrict__ bhh2,
    float* __restrict__ out,
    unsigned* ctl, unsigned* hr1, unsigned* hr2, float* xg1, float* xg2) {
  __shared__ alignas(16) char smem[126464];
  const int bx = blockIdx.x;
  const int xcd = bx & 7, idx = bx >> 3;   // empirical: dispatch round-robins XCDs
  if (xcd == 0)
    rec_fn<0>(Whh1, bhh1, ctl, hr1, hr2, xg1, out, idx, smem);
  else if (xcd == 1)
    rec_fn<1>(Whh2, bhh2, ctl, hr1, hr2, xg2, out, idx, smem);
  else if (xcd == 2)
    helper_fn<0>(x, Wih1, bih1, ctl, hr1, xg1, idx, smem);
  else if (xcd == 3)
    helper_fn<0>(x, Wih1, bih1, ctl, hr1, xg1, 4 + idx, smem);
  else if (xcd == 4)
    helper_fn<1>(x, Wih2, bih2, ctl, hr1, xg2, idx, smem);
  else if (xcd == 5)
    helper_fn<1>(x, Wih2, bih2, ctl, hr1, xg2, 4 + idx, smem);
  // xcd 6,7: idle
}

}  // namespace

extern "C" void kernel_launch(void* const* d_in, const int* in_sizes, int n_in,
                              void* d_out, int out_size, void* d_ws, size_t ws_size,
                              hipStream_t stream) {
  const float* x    = (const float*)d_in[0];
  const float* Wih1 = (const float*)d_in[1];
  const float* Whh1 = (const float*)d_in[2];
  const float* bih1 = (const float*)d_in[3];
  const float* bhh1 = (const float*)d_in[4];
  const float* Wih2 = (const float*)d_in[5];
  const float* Whh2 = (const float*)d_in[6];
  const float* bih2 = (const float*)d_in[7];
  const float* bhh2 = (const float*)d_in[8];

  unsigned* ctl = (unsigned*)d_ws;                                  // 4 KB (memset)
  unsigned* hr1 = (unsigned*)((char*)d_ws + 4096);                  // 1 MB
  unsigned* hr2 = hr1 + (size_t)NSLOT * SLOTU;                      // 1 MB
  float* xg1 = (float*)((char*)d_ws + 4096 + 2 * NSLOT * SLOTU * 4); // 3 MB
  float* xg2 = xg1 + (size_t)NSLOT * 16 * XROW;                      // 3 MB

  // progress words + xg tags must be zero at every launch
  hipMemsetAsync(d_ws, 0, 4096, stream);

  gru2_k<<<dim3(32), dim3(256), 0, stream>>>(
      x, Wih1, Whh1, bih1, bhh1, Wih2, Whh2, bih2, bhh2,
      (float*)d_out, ctl, hr1, hr2, xg1, xg2);
}

// Round 10
// 45623.569 us; speedup vs baseline: 1.0595x; 1.0595x over previous
//
#include <hip/hip_runtime.h>
#include <hip/hip_bf16.h>

// 2-layer GRU (torch gate order r,z,n) + residual, B=16 T=4096 IN=H=512.
//
// Round-10 = round-9 workers (unchanged) + HEATER blocks to defeat DVFS.
//  Evidence: four different sync protocols all pin at 9-12 us/step; VALUBusy
//  ~1%; identical dispatches vary 48->78 ms. Hypothesis: near-idle chip
//  downclocks ~5x; every latency in the chain is multiplied.
//  Fix: fill the other ~230 CUs with pure-VALU spin WGs (no memory traffic
//  except a rare done-flag poll). Workers use 126KB LDS -> 1 block/CU ->
//  heaters never share a CU with a worker.
//
// Worker architecture (identical to round 9):
//  - 4 rec WGs/layer (256 thr, W_hh quarter in 384 VGPR/lane), tag-in-data
//    h rings via sc0sc1 with sc0 (own-XCD L2) fast path; xg/y prefetch; 8
//    helper WGs/layer stream fp32 xg into 32-deep rings; rare back-pressure.

namespace {

constexpr int SEQ   = 4096;
constexpr int HD    = 512;
constexpr int NSLOT = 32;          // ring depth (steps)
constexpr int XROW  = 3 * HD;      // 1536 gate rows
constexpr int ROWS  = 528;         // LDS row pitch (u16)
constexpr int SLOTU = 16 * HD;     // u32 per h slot

typedef short    bf16x8 __attribute__((ext_vector_type(8)));
typedef float    f32x4  __attribute__((ext_vector_type(4)));
typedef unsigned u32x4  __attribute__((ext_vector_type(4)));

__device__ __forceinline__ unsigned short f2bf(float f) {
  unsigned u = __float_as_uint(f);
  return (unsigned short)((u + 0x7fffu + ((u >> 16) & 1u)) >> 16);  // RNE
}
__device__ __forceinline__ float bf2f(unsigned short s) {
  return __uint_as_float(((unsigned)s) << 16);
}
__device__ __forceinline__ unsigned pack2(float lo, float hi) {
  return (unsigned)f2bf(lo) | ((unsigned)f2bf(hi) << 16);
}
__device__ __forceinline__ float sigm(float v) { return 1.f / (1.f + __expf(-v)); }
__device__ __forceinline__ float tanh_(float v) { return 1.f - 2.f / (1.f + __expf(2.f * v)); }

__device__ __forceinline__ void ld_u32x4_nw(u32x4* d, const unsigned* p) {
  asm volatile("global_load_dwordx4 %0, %1, off sc0 sc1" : "=v"(*d) : "v"(p) : "memory");
}
// sc0-only: own-XCD L2 fast path (NOT authoritative cross-XCD; callers fall
// back to sc0sc1 on tag mismatch)
__device__ __forceinline__ void ld_u32x4_l2(u32x4* d, const unsigned* p) {
  asm volatile("global_load_dwordx4 %0, %1, off sc0" : "=v"(*d) : "v"(p) : "memory");
}
__device__ __forceinline__ void ld_f32x4_sc(f32x4* d, const float* p) {
  asm volatile("global_load_dwordx4 %0, %1, off sc0 sc1" : "=v"(*d) : "v"(p) : "memory");
}
__device__ __forceinline__ void st_u32_sc(unsigned* p, unsigned v) {
  asm volatile("global_store_dword %0, %1, off sc0 sc1" :: "v"(p), "v"(v) : "memory");
}
__device__ __forceinline__ void st_f32_sc(float* p, float v) {
  asm volatile("global_store_dword %0, %1, off sc0 sc1" :: "v"(p), "v"(v) : "memory");
}
__device__ __forceinline__ void st_u32x4_sc(unsigned* p, u32x4 v) {
  asm volatile("global_store_dwordx4 %0, %1, off sc0 sc1" :: "v"(p), "v"(v) : "memory");
}
__device__ __forceinline__ void vmwait0() {
  asm volatile("s_waitcnt vmcnt(0)" ::: "memory");
  __builtin_amdgcn_sched_barrier(0);   // rule #18
}

#define MFMA16(a, b, c) __builtin_amdgcn_mfma_f32_16x16x32_bf16((a), (b), (c), 0, 0, 0)

// hi16 extraction of 8 tagged granules -> 4x b128 LDS writes (padded rows)
__device__ __forceinline__ void stage_lds(const u32x4 (&v)[8], short* base, int b, int kc) {
  char* rowp = (char*)(base + b * ROWS + kc * 32);
  #pragma unroll
  for (int blk = 0; blk < 4; ++blk) {
    const int bb = blk ^ (kc & 3);
    const u32x4 a = v[bb * 2], d = v[bb * 2 + 1];
    u32x4 p;
    p[0] = (a[0] >> 16) | (a[1] & 0xffff0000u);
    p[1] = (a[2] >> 16) | (a[3] & 0xffff0000u);
    p[2] = (d[0] >> 16) | (d[1] & 0xffff0000u);
    p[3] = (d[2] >> 16) | (d[3] & 0xffff0000u);
    *(u32x4*)(rowp + bb * 16) = p;
  }
}

__device__ __forceinline__ void stage_x(const f32x4 (&xl)[8], short* base, int b, int kc) {
  char* rowp = (char*)(base + b * ROWS + kc * 32);
  #pragma unroll
  for (int blk = 0; blk < 4; ++blk) {
    const int bb = blk ^ (kc & 3);
    const f32x4 a = xl[bb * 2], d = xl[bb * 2 + 1];
    u32x4 p;
    p[0] = pack2(a[0], a[1]);
    p[1] = pack2(a[2], a[3]);
    p[2] = pack2(d[0], d[1]);
    p[3] = pack2(d[2], d[3]);
    *(u32x4*)(rowp + bb * 16) = p;
  }
}

// ---------------- recurrence WG: 256 thr, owns 128 units ----------------
template <int LAYER>
__device__ void rec_fn(const float* __restrict__ Whh, const float* __restrict__ bhh,
                       unsigned* ctl, unsigned* hr1, unsigned* hr2,
                       float* xgr, float* __restrict__ out, int s, char* smem) {
  short*    hstage = (short*)smem;                         // [2][16][528]  33792B
  float*    stash  = (float*)(smem + 33792);               // [2][256][24]  49152B
  unsigned* ylds   = (unsigned*)(smem + 33792 + 49152);    // [2][256][8]   16384B
  float*    gb     = (float*)(smem + 99328);               // [16][400]     25600B
  float*    bhl    = (float*)(smem + 124928);              // [384]          1536B

  const int tid = threadIdx.x;
  const int w = tid >> 6, lane = tid & 63, c = lane & 15, q = lane >> 4;
  const int b = tid >> 4, kc = tid & 15;      // staging + epilogue batch
  const int u0 = kc * 8;                      // epilogue unit base (local)

  unsigned* ownring = LAYER ? hr2 : hr1;
  unsigned* recprog = ctl + LAYER * 4;
  unsigned* xgtag   = ctl + 64 + LAYER * (NSLOT * 8);
  unsigned* recprog2 = ctl + 4;
  unsigned* xgtag2   = ctl + 64 + (NSLOT * 8);

  for (int i = tid; i < 384; i += 256) {
    const int g = i >> 7, u = i & 127;
    bhl[i] = bhh[g * HD + s * 128 + u];
  }
  // stationary W_hh: wave w -> local rows [w*96, w*96+96) (6 N-tiles)
  bf16x8 wf[6][16];
  #pragma unroll
  for (int nt = 0; nt < 6; ++nt) {
    const int lr = w * 96 + nt * 16 + c;
    const int g = lr >> 7, u = lr & 127;
    const float* pw = Whh + ((size_t)(g * HD + s * 128 + u)) * HD + q * 8;
    #pragma unroll
    for (int kk = 0; kk < 16; ++kk) {
      bf16x8 f;
      #pragma unroll
      for (int i = 0; i < 8; ++i) f[i] = (short)f2bf(pw[kk * 32 + i]);
      wf[nt][kk] = f;
    }
  }
  __syncthreads();

  f32x4 h0 = {0.f,0.f,0.f,0.f}, h1 = {0.f,0.f,0.f,0.f};  // own h fp32 (b,u0..u0+7)
  int haveXG = 0, haveY = 0;

  for (int t = 0; t < SEQ; ++t) {
    const int buf = t & 1, slot = t & (NSLOT - 1);
    // ------------- phase A -------------
    {
      if (LAYER == 0 && tid == 0 && t >= 32 && (t & 7) == 0) {
        // y-ring reuse: need L2 helpers + L2 rec past step t-24
        const unsigned need = (unsigned)(t - 23);
        const int ck = (t - 24) & (NSLOT - 1);
        for (;;) {
          u32x4 ta, tb, pr;
          ld_u32x4_nw(&ta, xgtag2 + ck * 8);
          ld_u32x4_nw(&tb, xgtag2 + ck * 8 + 4);
          ld_u32x4_nw(&pr, recprog2);
          vmwait0();
          bool ok = true;
          #pragma unroll
          for (int e = 0; e < 4; ++e)
            ok = ok && ta[e] >= need && tb[e] >= need && pr[e] >= need;
          if (ok) break;
          __builtin_amdgcn_s_sleep(32);
        }
      }
      // issue h loads (sc0 fast path) + xgtag(t+1) + y(t+1) together
      u32x4 hv[8];
      const unsigned htag = (unsigned)t;
      const unsigned* hp = ownring + (size_t)((t - 1) & (NSLOT - 1)) * SLOTU + b * HD + kc * 32;
      if (t > 0) {
        #pragma unroll
        for (int g2 = 0; g2 < 8; ++g2) ld_u32x4_l2(&hv[g2], hp + g2 * 4);
      }
      u32x4 tga = {0,0,0,0}, tgb = {0,0,0,0}, yv0 = {0,0,0,0}, yv1 = {0,0,0,0};
      const int nslot = (t + 1) & (NSLOT - 1);
      if (t + 1 < SEQ) {
        ld_u32x4_nw(&tga, xgtag + nslot * 8);
        ld_u32x4_nw(&tgb, xgtag + nslot * 8 + 4);
        if (LAYER == 1) {
          const unsigned* yp = hr1 + (size_t)nslot * SLOTU + b * HD + s * 128 + u0;
          ld_u32x4_nw(&yv0, yp);
          ld_u32x4_nw(&yv1, yp + 4);
        }
      }
      vmwait0();
      // h verify: sc0 result first; retries authoritative (sc0sc1), no sleep
      if (t > 0) {
        for (;;) {
          unsigned bad = 0;
          #pragma unroll
          for (int g2 = 0; g2 < 8; ++g2)
            #pragma unroll
            for (int e = 0; e < 4; ++e) bad |= hv[g2][e] ^ htag;
          if (!(bad & 0xffffu)) break;
          #pragma unroll
          for (int g2 = 0; g2 < 8; ++g2) ld_u32x4_nw(&hv[g2], hp + g2 * 4);
          vmwait0();
        }
        stage_lds(hv, hstage + buf * (16 * ROWS), b, kc);
      }
      // xg(t) fallback if not prefetched
      if (!haveXG) {
        const unsigned need = (unsigned)(t + 1);
        for (;;) {
          u32x4 ta, tb;
          ld_u32x4_nw(&ta, xgtag + slot * 8);
          ld_u32x4_nw(&tb, xgtag + slot * 8 + 4);
          vmwait0();
          bool ok = true;
          #pragma unroll
          for (int e = 0; e < 4; ++e) ok = ok && ta[e] == need && tb[e] == need;
          if (ok) break;
          __builtin_amdgcn_s_sleep(4);
        }
        f32x4 xv[6];
        const float* xp = xgr + ((size_t)slot * 16 + b) * XROW + s * 128 + u0;
        #pragma unroll
        for (int g2 = 0; g2 < 3; ++g2) {
          ld_f32x4_sc(&xv[g2 * 2],     xp + g2 * HD);
          ld_f32x4_sc(&xv[g2 * 2 + 1], xp + g2 * HD + 4);
        }
        vmwait0();
        float* st = stash + (buf * 256 + tid) * 24;
        #pragma unroll
        for (int g2 = 0; g2 < 6; ++g2) *(f32x4*)(st + g2 * 4) = xv[g2];
      }
      // y(t) fallback (L2 layer)
      if (LAYER == 1 && !haveY) {
        const unsigned need = (unsigned)(t + 1);
        const unsigned* yp = hr1 + (size_t)slot * SLOTU + b * HD + s * 128 + u0;
        u32x4 a0, a1;
        for (;;) {
          ld_u32x4_nw(&a0, yp);
          ld_u32x4_nw(&a1, yp + 4);
          vmwait0();
          unsigned bad = 0;
          #pragma unroll
          for (int e = 0; e < 4; ++e) bad |= (a0[e] ^ need) | (a1[e] ^ need);
          if (!(bad & 0xffffu)) break;
          __builtin_amdgcn_s_sleep(2);
        }
        unsigned* yd = ylds + (buf * 256 + tid) * 8;
        *(u32x4*)yd = a0;
        *(u32x4*)(yd + 4) = a1;
      }
      // prefetch xg(t+1) / y(t+1) if tags fresh
      haveXG = 0; haveY = 0;
      if (t + 1 < SEQ) {
        const unsigned need = (unsigned)(t + 2);
        bool okx = true;
        #pragma unroll
        for (int e = 0; e < 4; ++e) okx = okx && tga[e] == need && tgb[e] == need;
        if (okx) {
          f32x4 xv[6];
          const float* xp = xgr + ((size_t)nslot * 16 + b) * XROW + s * 128 + u0;
          #pragma unroll
          for (int g2 = 0; g2 < 3; ++g2) {
            ld_f32x4_sc(&xv[g2 * 2],     xp + g2 * HD);
            ld_f32x4_sc(&xv[g2 * 2 + 1], xp + g2 * HD + 4);
          }
          vmwait0();
          float* st = stash + ((buf ^ 1) * 256 + tid) * 24;
          #pragma unroll
          for (int g2 = 0; g2 < 6; ++g2) *(f32x4*)(st + g2 * 4) = xv[g2];
          haveXG = 1;
        }
        if (LAYER == 1) {
          unsigned bad = 0;
          #pragma unroll
          for (int e = 0; e < 4; ++e) bad |= (yv0[e] ^ need) | (yv1[e] ^ need);
          if (!(bad & 0xffffu)) {
            unsigned* yd = ylds + ((buf ^ 1) * 256 + tid) * 8;
            *(u32x4*)yd = yv0;
            *(u32x4*)(yd + 4) = yv1;
            haveY = 1;
          }
        }
      }
    }
    __syncthreads();  // B1
    if (tid == 255) st_u32_sc(&recprog[s], (unsigned)(t + 1));

    // ------------- matvec: 96 MFMA/wave -------------
    {
      f32x4 acc[6] = {{0.f,0.f,0.f,0.f},{0.f,0.f,0.f,0.f},{0.f,0.f,0.f,0.f},
                      {0.f,0.f,0.f,0.f},{0.f,0.f,0.f,0.f},{0.f,0.f,0.f,0.f}};
      if (t > 0) {
        const short* ap = hstage + buf * (16 * ROWS) + c * ROWS + q * 8;
        #pragma unroll
        for (int kk = 0; kk < 16; ++kk) {
          bf16x8 a = *(const bf16x8*)(ap + kk * 32);
          #pragma unroll
          for (int nt = 0; nt < 6; ++nt) acc[nt] = MFMA16(a, wf[nt][kk], acc[nt]);
        }
      }
      #pragma unroll
      for (int nt = 0; nt < 6; ++nt) {
        const int lr = w * 96 + nt * 16 + c;
        #pragma unroll
        for (int j = 0; j < 4; ++j) gb[(q * 4 + j) * 400 + lr] = acc[nt][j];
      }
    }
    __syncthreads();  // B2

    // ------------- epilogue -------------
    {
      const float* st = stash + (buf * 256 + tid) * 24;
      u32x4 pk0, pk1;
      float hv8[8];
      #pragma unroll
      for (int i = 0; i < 8; ++i) {
        const int u = u0 + i;
        const float xr_ = st[i], xz_ = st[8 + i], xn_ = st[16 + i];
        const float hr_ = gb[b * 400 + u] + bhl[u];
        const float hz_ = gb[b * 400 + 128 + u] + bhl[128 + u];
        const float hn_ = gb[b * 400 + 256 + u] + bhl[256 + u];
        const float r = sigm(xr_ + hr_);
        const float z = sigm(xz_ + hz_);
        const float nn = tanh_(xn_ + r * hn_);
        const float hp = (i < 4) ? h0[i & 3] : h1[i & 3];
        const float hv = (1.f - z) * nn + z * hp;
        if (i < 4) h0[i & 3] = hv; else h1[i & 3] = hv;
        hv8[i] = hv;
        const unsigned pw = ((unsigned)f2bf(hv) << 16) | (unsigned)(t + 1);
        if (i < 4) pk0[i & 3] = pw; else pk1[i & 3] = pw;
      }
      unsigned* op = ownring + (size_t)slot * SLOTU + b * HD + s * 128 + u0;
      st_u32x4_sc(op, pk0);
      st_u32x4_sc(op + 4, pk1);
      if (LAYER == 1) {
        const unsigned* yd = ylds + (buf * 256 + tid) * 8;
        f32x4 o0, o1;
        #pragma unroll
        for (int i = 0; i < 4; ++i) {
          o0[i] = hv8[i] + bf2f((unsigned short)(yd[i] >> 16));
          o1[i] = hv8[4 + i] + bf2f((unsigned short)(yd[4 + i] >> 16));
        }
        float* po = out + ((size_t)b * SEQ + t) * HD + s * 128 + u0;
        *(f32x4*)po = o0;
        *(f32x4*)(po + 4) = o1;
      }
    }
  }
  // layer-2 finishers release the heaters (flag zeroed each launch)
  if (LAYER == 1) {
    vmwait0();
    __syncthreads();
    if (tid == 0) st_u32_sc(ctl + 63, 1u);
  }
}

// ---------------- helper WG: xg producer, 192 rows ----------------
template <int LAYER>
__device__ void helper_fn(const float* __restrict__ x,
                          const float* __restrict__ Wih, const float* __restrict__ bih,
                          unsigned* ctl, unsigned* hr1, float* xgr, int h, char* smem) {
  short* astage = (short*)smem;   // [16][528]
  const int tid = threadIdx.x;
  const int w = tid >> 6, lane = tid & 63, c = lane & 15, q = lane >> 4;
  const int b = tid >> 4, kc = tid & 15;
  unsigned* recprog = ctl + LAYER * 4;
  unsigned* xgtag   = ctl + 64 + LAYER * (NSLOT * 8);

  bf16x8 wfh[3][16];
  float bias[3];
  #pragma unroll
  for (int ti = 0; ti < 3; ++ti) {
    const int grow = h * 192 + w * 48 + ti * 16 + c;
    bias[ti] = bih[grow];
    const float* pw = Wih + (size_t)grow * HD + q * 8;
    #pragma unroll
    for (int kk = 0; kk < 16; ++kk) {
      bf16x8 f;
      #pragma unroll
      for (int i = 0; i < 8; ++i) f[i] = (short)f2bf(pw[kk * 32 + i]);
      wfh[ti][kk] = f;
    }
  }

  // L1 helper: x(t) prefetched into registers one step ahead (tracked loads)
  f32x4 xl[8];
  if (LAYER == 0) {
    const float* px = x + (size_t)b * SEQ * HD + kc * 32;
    #pragma unroll
    for (int g2 = 0; g2 < 8; ++g2) xl[g2] = *(const f32x4*)(px + g2 * 4);
  }

  for (int t = 0; t < SEQ; ++t) {
    const int slot = t & (NSLOT - 1);
    if (tid == 0 && t >= NSLOT && (t & 7) == 0) {
      const unsigned need = (unsigned)(t - 16);
      for (;;) {
        u32x4 pr;
        ld_u32x4_nw(&pr, recprog);
        vmwait0();
        if (pr[0] >= need && pr[1] >= need && pr[2] >= need && pr[3] >= need) break;
        __builtin_amdgcn_s_sleep(32);
      }
    }
    if (LAYER == 0) {
      stage_x(xl, astage, b, kc);
      if (t + 1 < SEQ) {
        const float* px = x + ((size_t)b * SEQ + (t + 1)) * HD + kc * 32;
        #pragma unroll
        for (int g2 = 0; g2 < 8; ++g2) xl[g2] = *(const f32x4*)(px + g2 * 4);
      }
    } else {
      // poll y_t chunk (tag-in-data)
      u32x4 v0[8];
      const unsigned* yp = hr1 + (size_t)slot * SLOTU + b * HD + kc * 32;
      const unsigned need = (unsigned)(t + 1);
      #pragma unroll
      for (int g2 = 0; g2 < 8; ++g2) ld_u32x4_nw(&v0[g2], yp + g2 * 4);
      vmwait0();
      for (;;) {
        unsigned bad = 0;
        #pragma unroll
        for (int g2 = 0; g2 < 8; ++g2)
          #pragma unroll
          for (int e = 0; e < 4; ++e) bad |= v0[g2][e] ^ need;
        if (!(bad & 0xffffu)) break;
        __builtin_amdgcn_s_sleep(1);
        #pragma unroll
        for (int g2 = 0; g2 < 8; ++g2) ld_u32x4_nw(&v0[g2], yp + g2 * 4);
        vmwait0();
      }
      stage_lds(v0, astage, b, kc);
    }
    __syncthreads();  // stage ready

    f32x4 acc[3] = {{0.f,0.f,0.f,0.f},{0.f,0.f,0.f,0.f},{0.f,0.f,0.f,0.f}};
    const short* ap = astage + c * ROWS + q * 8;
    #pragma unroll
    for (int kk = 0; kk < 16; ++kk) {
      bf16x8 a = *(const bf16x8*)(ap + kk * 32);
      #pragma unroll
      for (int ti = 0; ti < 3; ++ti) acc[ti] = MFMA16(a, wfh[ti][kk], acc[ti]);
    }
    #pragma unroll
    for (int ti = 0; ti < 3; ++ti) {
      const int grow = h * 192 + w * 48 + ti * 16 + c;
      #pragma unroll
      for (int j = 0; j < 4; ++j)
        st_f32_sc(xgr + ((size_t)slot * 16 + (q * 4 + j)) * XROW + grow,
                  acc[ti][j] + bias[ti]);
    }
    vmwait0();
    __syncthreads();  // all stores acked
    if (tid == 0) st_u32_sc(&xgtag[slot * 8 + h], (unsigned)(t + 1));
  }
}

// ---------------- heater: pure-VALU spin to hold clocks up ----------------
__device__ void heater_fn(const unsigned* done) {
  float a0 = 1.0f + threadIdx.x, a1 = 1.1f, a2 = 1.2f, a3 = 1.3f;
  float a4 = 1.4f, a5 = 1.5f, a6 = 1.6f, a7 = 1.7f;
  const float bm = 1.0000001f, cm = 0.9999999f;
  for (;;) {
    #pragma unroll 1
    for (int i = 0; i < 4096; ++i) {
      asm volatile("v_fmac_f32 %0, %1, %2" : "+v"(a0) : "v"(bm), "v"(cm));
      asm volatile("v_fmac_f32 %0, %1, %2" : "+v"(a1) : "v"(bm), "v"(cm));
      asm volatile("v_fmac_f32 %0, %1, %2" : "+v"(a2) : "v"(bm), "v"(cm));
      asm volatile("v_fmac_f32 %0, %1, %2" : "+v"(a3) : "v"(bm), "v"(cm));
      asm volatile("v_fmac_f32 %0, %1, %2" : "+v"(a4) : "v"(bm), "v"(cm));
      asm volatile("v_fmac_f32 %0, %1, %2" : "+v"(a5) : "v"(bm), "v"(cm));
      asm volatile("v_fmac_f32 %0, %1, %2" : "+v"(a6) : "v"(bm), "v"(cm));
      asm volatile("v_fmac_f32 %0, %1, %2" : "+v"(a7) : "v"(bm), "v"(cm));
    }
    unsigned d;
    asm volatile("global_load_dword %0, %1, off sc0 sc1\n\ts_waitcnt vmcnt(0)"
                 : "=v"(d) : "v"(done) : "memory");
    if (d) break;
  }
  asm volatile("" :: "v"(a0), "v"(a1), "v"(a2), "v"(a3),
                     "v"(a4), "v"(a5), "v"(a6), "v"(a7));
}

__global__ __launch_bounds__(256, 1) void gru2_k(
    const float* __restrict__ x,
    const float* __restrict__ Wih1, const float* __restrict__ Whh1,
    const float* __restrict__ bih1, const float* __restrict__ bhh1,
    const float* __restrict__ Wih2, const float* __restrict__ Whh2,
    const float* __restrict__ bih2, const float* __restrict__ bhh2,
    float* __restrict__ out,
    unsigned* ctl, unsigned* hr1, unsigned* hr2, float* xg1, float* xg2) {
  __shared__ alignas(16) char smem[126464];
  const int bx = blockIdx.x;
  const int xcd = bx & 7, idx = bx >> 3;   // empirical: dispatch round-robins XCDs
  if (bx < 32 && xcd == 0)
    rec_fn<0>(Whh1, bhh1, ctl, hr1, hr2, xg1, out, idx, smem);
  else if (bx < 32 && xcd == 1)
    rec_fn<1>(Whh2, bhh2, ctl, hr1, hr2, xg2, out, idx, smem);
  else if (bx < 32 && xcd == 2)
    helper_fn<0>(x, Wih1, bih1, ctl, hr1, xg1, idx, smem);
  else if (bx < 32 && xcd == 3)
    helper_fn<0>(x, Wih1, bih1, ctl, hr1, xg1, 4 + idx, smem);
  else if (bx < 32 && xcd == 4)
    helper_fn<1>(x, Wih2, bih2, ctl, hr1, xg2, idx, smem);
  else if (bx < 32 && xcd == 5)
    helper_fn<1>(x, Wih2, bih2, ctl, hr1, xg2, 4 + idx, smem);
  else
    heater_fn(ctl + 63);   // bx 6,7,14,15,22,23,30,31 and all bx >= 32
}

}  // namespace

extern "C" void kernel_launch(void* const* d_in, const int* in_sizes, int n_in,
                              void* d_out, int out_size, void* d_ws, size_t ws_size,
                              hipStream_t stream) {
  const float* x    = (const float*)d_in[0];
  const float* Wih1 = (const float*)d_in[1];
  const float* Whh1 = (const float*)d_in[2];
  const float* bih1 = (const float*)d_in[3];
  const float* bhh1 = (const float*)d_in[4];
  const float* Wih2 = (const float*)d_in[5];
  const float* Whh2 = (const float*)d_in[6];
  const float* bih2 = (const float*)d_in[7];
  const float* bhh2 = (const float*)d_in[8];

  unsigned* ctl = (unsigned*)d_ws;                                  // 4 KB (memset)
  unsigned* hr1 = (unsigned*)((char*)d_ws + 4096);                  // 1 MB
  unsigned* hr2 = hr1 + (size_t)NSLOT * SLOTU;                      // 1 MB
  float* xg1 = (float*)((char*)d_ws + 4096 + 2 * NSLOT * SLOTU * 4); // 3 MB
  float* xg2 = xg1 + (size_t)NSLOT * 16 * XROW;                      // 3 MB

  // progress words + xg tags + done flag must be zero at every launch
  hipMemsetAsync(d_ws, 0, 4096, stream);

  gru2_k<<<dim3(256), dim3(256), 0, stream>>>(
      x, Wih1, Whh1, bih1, bhh1, Wih2, Whh2, bih2, bhh2,
      (float*)d_out, ctl, hr1, hr2, xg1, xg2);
}